// Round 2
// baseline (162.328 us; speedup 1.0000x reference)
//
#include <hip/hip_runtime.h>

#define N_IN 128
#define N_OUT 64
#define KNBR 32

// ---------- compile-time Batcher odd-even mergesort network for 16 ----------
struct Net {
  int a[64];
  int b[64];
  int n;
};

constexpr Net make_batcher16() {
  Net net{};
  net.n = 0;
  const int n = 16;
  for (int p = 1; p < n; p <<= 1)
    for (int k = p; k >= 1; k >>= 1)
      for (int j = k % p; j + k < n; j += 2 * k)
        for (int i = 0; i < k && i + j + k < n; ++i)
          if ((i + j) / (2 * p) == (i + j + k) / (2 * p)) {
            net.a[net.n] = i + j;
            net.b[net.n] = i + j + k;
            net.n++;
          }
  return net;
}

constexpr Net NET16 = make_batcher16();
static_assert(NET16.n == 63, "batcher16 comparator count must be 63");

__device__ __forceinline__ void cas(float& x, float& y) {
  float lo = fminf(x, y);
  float hi = fmaxf(x, y);
  x = lo;
  y = hi;
}

__device__ __forceinline__ float bcast(float v, int srclane) {
  return __int_as_float(__builtin_amdgcn_readlane(__float_as_int(v), srclane));
}

// ---------------- kernel 1: h = x @ W  (fp32 vector FMA) ----------------
// wave-per-row; W[:, lane] held in 128 VGPRs; x row broadcast via readlane.
__global__ __launch_bounds__(256) void gemm_kernel(
    const float* __restrict__ x, const float* __restrict__ W,
    float* __restrict__ h, int n) {
  const int lane = threadIdx.x & 63;
  const int wid = blockIdx.x * (blockDim.x >> 6) + (threadIdx.x >> 6);
  const int nw = gridDim.x * (blockDim.x >> 6);

  float w[N_IN];
#pragma unroll
  for (int k = 0; k < N_IN; ++k) w[k] = W[k * N_OUT + lane];

  for (int r = wid; r < n; r += nw) {
    const float* xr = x + (long)r * N_IN;
    float xlo = xr[lane];        // x[r][lane]
    float xhi = xr[64 + lane];   // x[r][64+lane]
    float acc = 0.f;
#pragma unroll
    for (int k = 0; k < 64; ++k) {
      acc = fmaf(bcast(xlo, k), w[k], acc);
      acc = fmaf(bcast(xhi, k), w[64 + k], acc);
    }
    h[(long)r * N_OUT + lane] = acc;
  }
}

// ---------------- kernel 2: gather 33 neighbors, exact median, +bias --------
// one wave per node; lane = output channel. 33 coalesced 256B row loads.
// edge_index dtype auto-detect: harness may deliver int32 or int64.
__global__ __launch_bounds__(256) void median_kernel(
    const float* __restrict__ h, const void* __restrict__ ei,
    const float* __restrict__ bias, float* __restrict__ out, int n) {
  const int lane = threadIdx.x & 63;
  const int node = blockIdx.x * (blockDim.x >> 6) + (threadIdx.x >> 6);
  if (node >= n) return;

  const int* e32 = (const int*)ei;
  const long long* e64 = (const long long*)ei;

  // int64 little-endian => high words (odd int32 slots) of first 8 elems are 0.
  // int32 random indices => essentially impossible. Wave-uniform result.
  bool is64 = (e32[1] == 0) && (e32[3] == 0) && (e32[5] == 0) &&
              (e32[7] == 0) && (e32[9] == 0) && (e32[11] == 0) &&
              (e32[13] == 0) && (e32[15] == 0);

  // lanes 0..31 hold the 32 neighbor indices
  const int pos = node * KNBR + (lane & 31);
  int idx;
  if (is64) {
    idx = (int)e64[pos];
  } else {
    idx = e32[pos];
  }

  float va[16], vb[16];
#pragma unroll
  for (int j = 0; j < 16; ++j) {
    int s = __builtin_amdgcn_readlane(idx, j);          // uniform SGPR index
    va[j] = h[(long)s * N_OUT + lane];                  // coalesced 256B row
  }
#pragma unroll
  for (int j = 0; j < 16; ++j) {
    int s = __builtin_amdgcn_readlane(idx, 16 + j);
    vb[j] = h[(long)s * N_OUT + lane];
  }
  float vx = h[(long)node * N_OUT + lane];              // self loop

  // sort the two 16-element halves (63 CAS each, all register-resident)
#pragma unroll
  for (int t = 0; t < NET16.n; ++t) cas(va[NET16.a[t]], va[NET16.b[t]]);
#pragma unroll
  for (int t = 0; t < NET16.n; ++t) cas(vb[NET16.a[t]], vb[NET16.b[t]]);

  // middle pair (ranks 15,16) of the merged 32 via crossing min/max:
  //   r15 = max_i min(va[i], vb[15-i]),  r16 = min_i max(va[i], vb[15-i])
  float r15 = -3.402823466e38f;
  float r16 = 3.402823466e38f;
#pragma unroll
  for (int i = 0; i < 16; ++i) {
    float lo = fminf(va[i], vb[15 - i]);
    float hi = fmaxf(va[i], vb[15 - i]);
    r15 = fmaxf(r15, lo);
    r16 = fminf(r16, hi);
  }

  // median of 33 = clamp(self, r15, r16)  (exact order statistic)
  float med = fmaxf(r15, fminf(vx, r16));
  out[(long)node * N_OUT + lane] = med + bias[lane];
}

extern "C" void kernel_launch(void* const* d_in, const int* in_sizes, int n_in,
                              void* d_out, int out_size, void* d_ws, size_t ws_size,
                              hipStream_t stream) {
  const float* x = (const float*)d_in[0];
  const void* ei = d_in[1];  // [2, E]; row = first E; int32 or int64
  const float* W = (const float*)d_in[2];
  const float* b = (const float*)d_in[3];
  float* out = (float*)d_out;
  float* h = (float*)d_ws;  // [n, 64] fp32 scratch = 25.6 MB

  const int n = in_sizes[0] / N_IN;  // 100000

  gemm_kernel<<<1536, 256, 0, stream>>>(x, W, h, n);

  const int nodes_per_block = 256 / 64;
  const int grid = (n + nodes_per_block - 1) / nodes_per_block;
  median_kernel<<<grid, 256, 0, stream>>>(h, ei, b, out, n);
}

// Round 3
// 127.026 us; speedup vs baseline: 1.2779x; 1.2779x over previous
//
#include <hip/hip_runtime.h>
#include <hip/hip_bf16.h>

#define N_IN 128
#define N_OUT 64
#define KNBR 32

// ---------- compile-time Batcher odd-even mergesort network for 16 ----------
struct Net {
  int a[64];
  int b[64];
  int n;
};

constexpr Net make_batcher16() {
  Net net{};
  net.n = 0;
  const int n = 16;
  for (int p = 1; p < n; p <<= 1)
    for (int k = p; k >= 1; k >>= 1)
      for (int j = k % p; j + k < n; j += 2 * k)
        for (int i = 0; i < k && i + j + k < n; ++i)
          if ((i + j) / (2 * p) == (i + j + k) / (2 * p)) {
            net.a[net.n] = i + j;
            net.b[net.n] = i + j + k;
            net.n++;
          }
  return net;
}

constexpr Net NET16 = make_batcher16();
static_assert(NET16.n == 63, "batcher16 comparator count must be 63");

__device__ __forceinline__ void cas(float& x, float& y) {
  float lo = fminf(x, y);
  float hi = fmaxf(x, y);
  x = lo;
  y = hi;
}

// ---------------- kernel 1: h = x @ W  (fp32 FMA, bf16 output) ----------------
// wave-per-row; W[:, lane] pinned in 128 VGPRs; x-row broadcast via LDS
// ds_read_b128 at wave-uniform address (LGKM pipe, parallel to VALU);
// next row's x prefetched under the current row's 128 FMAs.
__global__ __launch_bounds__(256) void gemm_kernel(
    const float* __restrict__ x, const float* __restrict__ W,
    __hip_bfloat16* __restrict__ h, int n) {
  __shared__ float xs[4][N_IN];
  const int lane = threadIdx.x & 63;
  const int wslot = threadIdx.x >> 6;
  const int wid = blockIdx.x * (blockDim.x >> 6) + wslot;
  const int nw = gridDim.x * (blockDim.x >> 6);

  float w[N_IN];
#pragma unroll
  for (int k = 0; k < N_IN; ++k) w[k] = W[k * N_OUT + lane];

  int r = wid;
  if (r >= n) return;
  float2 xv = *(const float2*)(x + (size_t)r * N_IN + lane * 2);
  while (r < n) {
    const int rn = r + nw;
    float2 xnext = xv;
    if (rn < n) xnext = *(const float2*)(x + (size_t)rn * N_IN + lane * 2);

    ((float2*)xs[wslot])[lane] = xv;  // wave-coherent LDS stage (512 B)
    float a0 = 0.f, a1 = 0.f, a2 = 0.f, a3 = 0.f;
#pragma unroll
    for (int kk = 0; kk < 32; ++kk) {
      float4 xq = ((const float4*)xs[wslot])[kk];  // uniform addr -> broadcast
      a0 = fmaf(xq.x, w[4 * kk + 0], a0);
      a1 = fmaf(xq.y, w[4 * kk + 1], a1);
      a2 = fmaf(xq.z, w[4 * kk + 2], a2);
      a3 = fmaf(xq.w, w[4 * kk + 3], a3);
    }
    h[(size_t)r * N_OUT + lane] = __float2bfloat16((a0 + a1) + (a2 + a3));
    xv = xnext;
    r = rn;
  }
}

// ---------------- kernel 2: gather 33 bf16 rows, exact median, +bias --------
// one wave per node; lane = output channel. 33 coalesced 128B row loads.
__global__ __launch_bounds__(256) void median_kernel(
    const ushort* __restrict__ h, const void* __restrict__ ei,
    const float* __restrict__ bias, float* __restrict__ out, int n) {
  const int lane = threadIdx.x & 63;
  const int node = blockIdx.x * (blockDim.x >> 6) + (threadIdx.x >> 6);
  if (node >= n) return;

  const int* e32 = (const int*)ei;
  const long long* e64 = (const long long*)ei;

  // int64 little-endian => high words (odd int32 slots) of first 8 elems are 0.
  bool is64 = (e32[1] == 0) && (e32[3] == 0) && (e32[5] == 0) &&
              (e32[7] == 0) && (e32[9] == 0) && (e32[11] == 0) &&
              (e32[13] == 0) && (e32[15] == 0);

  const int pos = node * KNBR + (lane & 31);
  int idx;
  if (is64) {
    idx = (int)e64[pos];
  } else {
    idx = e32[pos];
  }

  ushort ua[16], ub[16];
#pragma unroll
  for (int j = 0; j < 16; ++j) {
    int s = __builtin_amdgcn_readlane(idx, j);           // uniform SGPR index
    ua[j] = h[(size_t)s * N_OUT + lane];                 // coalesced 128B row
  }
#pragma unroll
  for (int j = 0; j < 16; ++j) {
    int s = __builtin_amdgcn_readlane(idx, 16 + j);
    ub[j] = h[(size_t)s * N_OUT + lane];
  }
  ushort ux = h[(size_t)node * N_OUT + lane];            // self loop

  float va[16], vb[16];
#pragma unroll
  for (int j = 0; j < 16; ++j) va[j] = __uint_as_float((unsigned)ua[j] << 16);
#pragma unroll
  for (int j = 0; j < 16; ++j) vb[j] = __uint_as_float((unsigned)ub[j] << 16);
  float vx = __uint_as_float((unsigned)ux << 16);

  // sort the two 16-element halves (63 CAS each, register-resident)
#pragma unroll
  for (int t = 0; t < NET16.n; ++t) cas(va[NET16.a[t]], va[NET16.b[t]]);
#pragma unroll
  for (int t = 0; t < NET16.n; ++t) cas(vb[NET16.a[t]], vb[NET16.b[t]]);

  // middle pair (ranks 15,16) of merged 32 via crossing min/max
  float r15 = -3.402823466e38f;
  float r16 = 3.402823466e38f;
#pragma unroll
  for (int i = 0; i < 16; ++i) {
    float lo = fminf(va[i], vb[15 - i]);
    float hi = fmaxf(va[i], vb[15 - i]);
    r15 = fmaxf(r15, lo);
    r16 = fminf(r16, hi);
  }

  // median of 33 = clamp(self, r15, r16)  (exact order statistic)
  float med = fmaxf(r15, fminf(vx, r16));
  out[(size_t)node * N_OUT + lane] = med + bias[lane];
}

extern "C" void kernel_launch(void* const* d_in, const int* in_sizes, int n_in,
                              void* d_out, int out_size, void* d_ws, size_t ws_size,
                              hipStream_t stream) {
  const float* x = (const float*)d_in[0];
  const void* ei = d_in[1];  // [2, E]; row = first E; int32 or int64
  const float* W = (const float*)d_in[2];
  const float* b = (const float*)d_in[3];
  float* out = (float*)d_out;
  __hip_bfloat16* h = (__hip_bfloat16*)d_ws;  // [n, 64] bf16 scratch = 12.8 MB

  const int n = in_sizes[0] / N_IN;  // 100000

  gemm_kernel<<<2048, 256, 0, stream>>>(x, W, h, n);

  const int nodes_per_block = 256 / 64;
  const int grid = (n + nodes_per_block - 1) / nodes_per_block;
  median_kernel<<<grid, 256, 0, stream>>>((const ushort*)h, ei, b, out, n);
}